// Round 6
// baseline (212.899 us; speedup 1.0000x reference)
//
#include <hip/hip_runtime.h>
#include <math.h>

#define NN 4194304
#define NG 8192
#define TSTEPS 1000

// ws layout (floats): [0]=alpha, [1]=sigma, [4..4+8192] = start[] (ints, 8193)

// Parallel clipped-cumprod: step_j = clip(A[j+1]/A[j], 1e-3, 1) with
// A[0]=1, A[j+1]=(1-(j/T)^3)^2. P_t = prod_{j<=t} step_j (tree reduction).
__global__ __launch_bounds__(256) void k_alpha(const int* __restrict__ t_ptr,
                                               float* __restrict__ wsf) {
    int t = t_ptr[0];
    int tid = threadIdx.x;
    double partial = 1.0;
    #pragma unroll
    for (int k = 0; k < 4; ++k) {
        int j = tid * 4 + k;                 // covers 0..1023 >= TSTEPS
        if (j <= TSTEPS && j <= t) {
            double xj = (double)j / (double)TSTEPS;
            double num = 1.0 - xj * xj * xj; num *= num;      // A[j+1]
            double den = 1.0;                                  // A[j]
            if (j > 0) {
                double xp = (double)(j - 1) / (double)TSTEPS;
                den = 1.0 - xp * xp * xp; den *= den;
            }
            double step = num / den;
            step = fmin(fmax(step, 0.001), 1.0);
            partial *= step;
        }
    }
    #pragma unroll
    for (int off = 1; off < 64; off <<= 1)
        partial *= __shfl_xor(partial, off);
    __shared__ double wprod[4];
    int lane = tid & 63, wid = tid >> 6;
    if (lane == 0) wprod[wid] = partial;
    __syncthreads();
    if (tid == 0) {
        double P = wprod[0] * wprod[1] * wprod[2] * wprod[3];
        double at = (1.0 - 2.0e-4) * P + 1.0e-4;
        wsf[0] = (float)at;
        wsf[1] = (float)sqrt(1.0 - at * at);
    }
}

// start[s] = first index i with batch_index[i] >= s, for s in [0, NG]; start[NG]=N.
// Sorted input -> boundary detection; gap-fill covers empty segments.
__global__ void k_bounds(const int* __restrict__ bidx, int* __restrict__ start, int n) {
    int i = blockIdx.x * blockDim.x + threadIdx.x;
    if (i >= n) return;
    int b = bidx[i];
    if (i == 0) {
        for (int s = 0; s <= b; ++s) start[s] = 0;
    } else {
        int pb = bidx[i - 1];
        for (int s = pb + 1; s <= b; ++s) start[s] = i;
    }
    if (i == n - 1) {
        for (int s = b + 1; s <= NG; ++s) start[s] = n;
    }
}

// ONE WAVE PER SEGMENT, 4 segments per 256-thread block.
// 2048 blocks x 4 waves = 8192 waves = full-chip co-residency (32 waves/CU).
// No LDS, no __syncthreads: 64-lane shuffle reduce + broadcast. Both passes
// use 3x float4 per 4-node group; <=3 scalar edge nodes per segment side.
__global__ __launch_bounds__(256) void k_fused(const float* __restrict__ noise,
                                               const float* __restrict__ z,
                                               const int* __restrict__ start,
                                               const float* __restrict__ wsf,
                                               float* __restrict__ out) {
    int s = blockIdx.x * 4 + (threadIdx.x >> 6);
    int lane = threadIdx.x & 63;
    int rs = start[s], re = start[s + 1];
    int cnt = re - rs;
    int a0 = (rs + 3) >> 2;       // first full 4-node group
    int a1 = re >> 2;             // end group (exclusive)
    int e0 = a0 * 4 - rs;         // leading scalar nodes (0..3)
    int e1 = re - a1 * 4;         // trailing scalar nodes (0..3)
    const float4* np = (const float4*)noise;
    const float4* zp = (const float4*)z;
    bool vec = (a1 > a0);

    float sx = 0.f, sy = 0.f, sz = 0.f;
    if (vec) {
        for (int g = a0 + lane; g < a1; g += 64) {
            size_t p = (size_t)g * 3;
            float4 n0 = np[p], n1 = np[p + 1], n2 = np[p + 2];
            // lanes: n0=(x0,y0,z0,x1) n1=(y1,z1,x2,y2) n2=(z2,x3,y3,z3)
            sx += n0.x + n0.w + n1.z + n2.y;
            sy += n0.y + n1.x + n1.w + n2.z;
            sz += n0.z + n1.y + n2.x + n2.w;
        }
        if (lane < e0) {
            int i = rs + lane;
            sx += noise[3 * i]; sy += noise[3 * i + 1]; sz += noise[3 * i + 2];
        }
        if (lane >= 4 && lane < 4 + e1) {
            int i = a1 * 4 + lane - 4;
            sx += noise[3 * i]; sy += noise[3 * i + 1]; sz += noise[3 * i + 2];
        }
    } else {
        for (int i = rs + lane; i < re; i += 64) {
            sx += noise[3 * i]; sy += noise[3 * i + 1]; sz += noise[3 * i + 2];
        }
    }
    #pragma unroll
    for (int off = 32; off > 0; off >>= 1) {
        sx += __shfl_down(sx, off);
        sy += __shfl_down(sy, off);
        sz += __shfl_down(sz, off);
    }
    float inv = 1.0f / (float)(cnt > 1 ? cnt : 1);
    float mx = __shfl(sx, 0) * inv;
    float my = __shfl(sy, 0) * inv;
    float mz = __shfl(sz, 0) * inv;
    float alpha = wsf[0], sigma = wsf[1];

    float4* oz = (float4*)out;
    float4* oc = (float4*)(out + (size_t)NN * 3);
    float* ozs = out;
    float* ocs = out + (size_t)NN * 3;

    if (vec) {
        for (int g = a0 + lane; g < a1; g += 64) {
            size_t p = (size_t)g * 3;
            float4 n0 = np[p], n1 = np[p + 1], n2 = np[p + 2];
            float4 z0 = zp[p], z1 = zp[p + 1], z2 = zp[p + 2];
            float4 c0, c1, c2;
            c0.x = n0.x - mx; c0.y = n0.y - my; c0.z = n0.z - mz; c0.w = n0.w - mx;
            c1.x = n1.x - my; c1.y = n1.y - mz; c1.z = n1.z - mx; c1.w = n1.w - my;
            c2.x = n2.x - mz; c2.y = n2.y - mx; c2.z = n2.z - my; c2.w = n2.w - mz;
            float4 a0v, a1v, a2v;
            a0v.x = alpha * z0.x + sigma * c0.x; a0v.y = alpha * z0.y + sigma * c0.y;
            a0v.z = alpha * z0.z + sigma * c0.z; a0v.w = alpha * z0.w + sigma * c0.w;
            a1v.x = alpha * z1.x + sigma * c1.x; a1v.y = alpha * z1.y + sigma * c1.y;
            a1v.z = alpha * z1.z + sigma * c1.z; a1v.w = alpha * z1.w + sigma * c1.w;
            a2v.x = alpha * z2.x + sigma * c2.x; a2v.y = alpha * z2.y + sigma * c2.y;
            a2v.z = alpha * z2.z + sigma * c2.z; a2v.w = alpha * z2.w + sigma * c2.w;
            oz[p] = a0v; oz[p + 1] = a1v; oz[p + 2] = a2v;
            oc[p] = c0;  oc[p + 1] = c1;  oc[p + 2] = c2;
        }
        int i = -1;
        if (lane < e0) i = rs + lane;
        else if (lane >= 4 && lane < 4 + e1) i = a1 * 4 + lane - 4;
        if (i >= 0) {
            float cx = noise[3 * i]     - mx;
            float cy = noise[3 * i + 1] - my;
            float cz = noise[3 * i + 2] - mz;
            ozs[3 * i]     = alpha * z[3 * i]     + sigma * cx;
            ozs[3 * i + 1] = alpha * z[3 * i + 1] + sigma * cy;
            ozs[3 * i + 2] = alpha * z[3 * i + 2] + sigma * cz;
            ocs[3 * i] = cx; ocs[3 * i + 1] = cy; ocs[3 * i + 2] = cz;
        }
    } else {
        for (int i = rs + lane; i < re; i += 64) {
            float cx = noise[3 * i]     - mx;
            float cy = noise[3 * i + 1] - my;
            float cz = noise[3 * i + 2] - mz;
            ozs[3 * i]     = alpha * z[3 * i]     + sigma * cx;
            ozs[3 * i + 1] = alpha * z[3 * i + 1] + sigma * cy;
            ozs[3 * i + 2] = alpha * z[3 * i + 2] + sigma * cz;
            ocs[3 * i] = cx; ocs[3 * i + 1] = cy; ocs[3 * i + 2] = cz;
        }
    }
}

extern "C" void kernel_launch(void* const* d_in, const int* in_sizes, int n_in,
                              void* d_out, int out_size, void* d_ws, size_t ws_size,
                              hipStream_t stream) {
    const float* z     = (const float*)d_in[0];
    const float* noise = (const float*)d_in[1];
    const int*   bidx  = (const int*)d_in[2];
    const int*   t     = (const int*)d_in[3];
    float* out = (float*)d_out;

    float* wsf   = (float*)d_ws;
    int*   start = (int*)(wsf + 4);

    k_alpha<<<1, 256, 0, stream>>>(t, wsf);
    k_bounds<<<NN / 256, 256, 0, stream>>>(bidx, start, NN);
    k_fused<<<NG / 4, 256, 0, stream>>>(noise, z, start, wsf, out);
}

// Round 7
// 201.609 us; speedup vs baseline: 1.0560x; 1.0560x over previous
//
#include <hip/hip_runtime.h>
#include <math.h>

#define NN 4194304
#define NG 8192
#define TSTEPS 1000

typedef float fv4 __attribute__((ext_vector_type(4)));

// ws layout (floats): [0]=alpha, [1]=sigma, [4..4+8192] = start[] (ints, 8193)

// Parallel clipped-cumprod: step_j = clip(A[j+1]/A[j], 1e-3, 1) with
// A[0]=1, A[j+1]=(1-(j/T)^3)^2. P_t = prod_{j<=t} step_j (tree reduction).
__global__ __launch_bounds__(256) void k_alpha(const int* __restrict__ t_ptr,
                                               float* __restrict__ wsf) {
    int t = t_ptr[0];
    int tid = threadIdx.x;
    double partial = 1.0;
    #pragma unroll
    for (int k = 0; k < 4; ++k) {
        int j = tid * 4 + k;                 // covers 0..1023 >= TSTEPS
        if (j <= TSTEPS && j <= t) {
            double xj = (double)j / (double)TSTEPS;
            double num = 1.0 - xj * xj * xj; num *= num;      // A[j+1]
            double den = 1.0;                                  // A[j]
            if (j > 0) {
                double xp = (double)(j - 1) / (double)TSTEPS;
                den = 1.0 - xp * xp * xp; den *= den;
            }
            double step = num / den;
            step = fmin(fmax(step, 0.001), 1.0);
            partial *= step;
        }
    }
    #pragma unroll
    for (int off = 1; off < 64; off <<= 1)
        partial *= __shfl_xor(partial, off);
    __shared__ double wprod[4];
    int lane = tid & 63, wid = tid >> 6;
    if (lane == 0) wprod[wid] = partial;
    __syncthreads();
    if (tid == 0) {
        double P = wprod[0] * wprod[1] * wprod[2] * wprod[3];
        double at = (1.0 - 2.0e-4) * P + 1.0e-4;
        wsf[0] = (float)at;
        wsf[1] = (float)sqrt(1.0 - at * at);
    }
}

// start[s] = first index i with batch_index[i] >= s, for s in [0, NG]; start[NG]=N.
// Sorted input -> boundary detection; gap-fill covers empty segments.
__global__ void k_bounds(const int* __restrict__ bidx, int* __restrict__ start, int n) {
    int i = blockIdx.x * blockDim.x + threadIdx.x;
    if (i >= n) return;
    int b = bidx[i];
    if (i == 0) {
        for (int s = 0; s <= b; ++s) start[s] = 0;
    } else {
        int pb = bidx[i - 1];
        for (int s = pb + 1; s <= b; ++s) start[s] = i;
    }
    if (i == n - 1) {
        for (int s = b + 1; s <= NG; ++s) start[s] = n;
    }
}

// One 256-thread block per segment. FLAT-FLOAT4 indexing: the segment's
// 3*cnt floats are a flat float4 array; thread t handles q = q0+t, q0+t+256...
// -> every vec-mem instruction is 64-lane unit-stride (1 KiB dense, fill-like).
// Component of float f is f%3; since 4q == q (mod 3), each float4 has phase
// r = q%3 selecting the xyz routing (pass 1) / broadcast mean vector (pass 2).
__global__ __launch_bounds__(256) void k_fused(const float* __restrict__ noise,
                                               const float* __restrict__ z,
                                               const int* __restrict__ start,
                                               const float* __restrict__ wsf,
                                               float* __restrict__ out) {
    int s = blockIdx.x;
    int rs = start[s], re = start[s + 1];
    int cnt = re - rs;
    int tid = threadIdx.x;
    int f0 = 3 * rs, f1 = 3 * re;
    int q0 = (f0 + 3) >> 2;       // first full float4
    int q1 = f1 >> 2;             // end float4 (exclusive)
    int e0 = q0 * 4 - f0;         // leading floats (0..3)
    int e1 = f1 - q1 * 4;         // trailing floats (0..3)
    const fv4* np = (const fv4*)noise;
    const fv4* zp = (const fv4*)z;
    bool vec = (q1 > q0);

    float sx = 0.f, sy = 0.f, sz = 0.f;
    if (vec) {
        for (int q = q0 + tid; q < q1; q += 256) {
            fv4 v = np[q];
            int r = q % 3;
            if (r == 0)      { sx += v.x + v.w; sy += v.y; sz += v.z; }
            else if (r == 1) { sy += v.x + v.w; sz += v.y; sx += v.z; }
            else             { sz += v.x + v.w; sx += v.y; sy += v.z; }
        }
        if (tid < e0) {
            int f = f0 + tid; int r = f % 3; float v = noise[f];
            if (r == 0) sx += v; else if (r == 1) sy += v; else sz += v;
        }
        if (tid >= 4 && tid < 4 + e1) {
            int f = q1 * 4 + tid - 4; int r = f % 3; float v = noise[f];
            if (r == 0) sx += v; else if (r == 1) sy += v; else sz += v;
        }
    } else {
        for (int f = f0 + tid; f < f1; f += 256) {
            int r = f % 3; float v = noise[f];
            if (r == 0) sx += v; else if (r == 1) sy += v; else sz += v;
        }
    }
    #pragma unroll
    for (int off = 32; off > 0; off >>= 1) {
        sx += __shfl_down(sx, off);
        sy += __shfl_down(sy, off);
        sz += __shfl_down(sz, off);
    }
    __shared__ float red[3][4];
    __shared__ float mvs[3];
    int lane = tid & 63, wid = tid >> 6;
    if (lane == 0) { red[0][wid] = sx; red[1][wid] = sy; red[2][wid] = sz; }
    __syncthreads();
    if (tid == 0) {
        float inv = 1.0f / (float)(cnt > 1 ? cnt : 1);
        mvs[0] = (red[0][0] + red[0][1] + red[0][2] + red[0][3]) * inv;
        mvs[1] = (red[1][0] + red[1][1] + red[1][2] + red[1][3]) * inv;
        mvs[2] = (red[2][0] + red[2][1] + red[2][2] + red[2][3]) * inv;
    }
    __syncthreads();
    float mx = mvs[0], my = mvs[1], mz = mvs[2];
    float alpha = wsf[0], sigma = wsf[1];

    fv4* oz4 = (fv4*)out;
    fv4* oc4 = (fv4*)(out + (size_t)NN * 3);

    if (vec) {
        for (int q = q0 + tid; q < q1; q += 256) {
            fv4 n4 = np[q];
            fv4 z4 = __builtin_nontemporal_load(&zp[q]);
            int r = q % 3;
            fv4 mv;
            if (r == 0)      mv = (fv4){mx, my, mz, mx};
            else if (r == 1) mv = (fv4){my, mz, mx, my};
            else             mv = (fv4){mz, mx, my, mz};
            fv4 c4 = n4 - mv;
            fv4 o4 = alpha * z4 + sigma * c4;
            __builtin_nontemporal_store(o4, &oz4[q]);
            __builtin_nontemporal_store(c4, &oc4[q]);
        }
        int f = -1;
        if (tid < e0) f = f0 + tid;
        else if (tid >= 4 && tid < 4 + e1) f = q1 * 4 + tid - 4;
        if (f >= 0) {
            int r = f % 3;
            float m = (r == 0) ? mx : (r == 1) ? my : mz;
            float c = noise[f] - m;
            out[f] = alpha * z[f] + sigma * c;
            out[(size_t)NN * 3 + f] = c;
        }
    } else {
        for (int f = f0 + tid; f < f1; f += 256) {
            int r = f % 3;
            float m = (r == 0) ? mx : (r == 1) ? my : mz;
            float c = noise[f] - m;
            out[f] = alpha * z[f] + sigma * c;
            out[(size_t)NN * 3 + f] = c;
        }
    }
}

extern "C" void kernel_launch(void* const* d_in, const int* in_sizes, int n_in,
                              void* d_out, int out_size, void* d_ws, size_t ws_size,
                              hipStream_t stream) {
    const float* z     = (const float*)d_in[0];
    const float* noise = (const float*)d_in[1];
    const int*   bidx  = (const int*)d_in[2];
    const int*   t     = (const int*)d_in[3];
    float* out = (float*)d_out;

    float* wsf   = (float*)d_ws;
    int*   start = (int*)(wsf + 4);

    k_alpha<<<1, 256, 0, stream>>>(t, wsf);
    k_bounds<<<NN / 256, 256, 0, stream>>>(bidx, start, NN);
    k_fused<<<NG, 256, 0, stream>>>(noise, z, start, wsf, out);
}